// Round 1
// 146.817 us; speedup vs baseline: 1.0197x; 1.0197x over previous
//
#include <hip/hip_runtime.h>
#include <hip/hip_bf16.h>
#include <cstdint>
#include <cstddef>

#define B_N   32
#define CIN_  128
#define COUT_ 128
#define KW_   7
#define L_    4096
#define PAD_  3
#define NW_   256      // w-positions per block tile (was 128)
#define BC_   32       // channels per K-chunk
#define RPB   4104     // exT rows per batch: r = l + 3, guards r<3 and r>4098
#define NWELEM (KW_ * COUT_ * CIN_)   // 114688
#define NGUARD (B_N * 8 * CIN_)       // 32768

#define SW_ELEMS (KW_ * COUT_ * BC_)  // 28672 bf16 = 57344 B
#define SX_ROWS  320                  // 262 used; padded so granules % 256 == 0
#define SX_ELEMS (SX_ROWS * BC_)      // 10240 bf16 = 20480 B
#define NGRAN_W  (SW_ELEMS / 8)       // 3584 granules = 14 rounds of 256
#define NGRAN_T  ((SW_ELEMS + SX_ELEMS) / 8)  // 4864 = 19 * 256

typedef __attribute__((ext_vector_type(8))) short  bf16x8;
typedef __attribute__((ext_vector_type(4))) float  f32x4;

__device__ __forceinline__ void gl2lds16(const void* g, void* l) {
    __builtin_amdgcn_global_load_lds(
        (const __attribute__((address_space(1))) unsigned int*)g,
        (__attribute__((address_space(3))) unsigned int*)l, 16, 0, 0);
}

// exp+transpose of x (blocks x<64), plus weight-exp and exT guard-row zeroing
// (blocks x>=64, y==0) folded in to save a kernel launch.
__global__ __launch_bounds__(256) void exp_x_kernel(
        const float* __restrict__ x, __hip_bfloat16* __restrict__ exT,
        const float* __restrict__ w, __hip_bfloat16* __restrict__ ewb) {
    if (blockIdx.x >= 64) {
        if (blockIdx.y != 0) return;
        int base = (blockIdx.x - 64) * 256 + threadIdx.x;   // 18 blocks * 256 = 4608
        #pragma unroll
        for (int i = 0; i < 32; ++i) {
            int idx = base + 4608 * i;                      // covers 147456 = NWELEM+NGUARD
            if (idx < NWELEM) {
                int c = idx & 127, rest = idx >> 7;
                int o = rest & 127, k = rest >> 7;
                ewb[idx] = __float2bfloat16(__expf(w[(o * CIN_ + c) * KW_ + k]));
            } else {
                int j  = idx - NWELEM;
                int b  = j >> 10, rr = (j >> 7) & 7, c = j & 127;
                int r  = (rr < 3) ? rr : (4096 + rr);       // rows 0,1,2 and 4099..4103
                exT[((size_t)b * RPB + r) * CIN_ + c] = __float2bfloat16(0.0f);
            }
        }
        return;
    }

    __shared__ __align__(16) __hip_bfloat16 tileT[64 * 136];   // 17408 B
    const int b  = blockIdx.y;
    const int l0 = blockIdx.x * 64;
    const int tid = threadIdx.x;
    const float* xb = x + (size_t)b * CIN_ * L_ + l0;

    #pragma unroll
    for (int i = 0; i < 8; ++i) {
        int idx = tid + 256 * i;
        int c   = idx >> 4;               // 0..127
        int lv4 = (idx & 15) * 4;         // l offset 0..60
        f32x4 v = *(const f32x4*)(xb + (size_t)c * L_ + lv4);
        #pragma unroll
        for (int k2 = 0; k2 < 4; ++k2) {
            int l  = lv4 + k2;
            int sw = (l >> 2) & 15;
            tileT[l * 136 + (c ^ (sw << 3))] = __float2bfloat16(__expf(v[k2]));
        }
    }
    __syncthreads();

    __hip_bfloat16* dst = exT + ((size_t)b * RPB + l0 + PAD_) * CIN_;
    #pragma unroll
    for (int i = 0; i < 4; ++i) {
        int idx = tid + 256 * i;
        int l  = idx >> 4;                // 16 lanes per row -> 256 B coalesced
        int gc = idx & 15;                // channel granule (8 ch)
        int sw = (l >> 2) & 15;
        bf16x8 vv = *(const bf16x8*)&tileT[l * 136 + ((gc ^ sw) << 3)];
        *(bf16x8*)(dst + (size_t)l * CIN_ + gc * 8) = vv;
    }
}

// Conv GEMM. Per 32-ch chunk: stage sW (56KB, MFMA-fragment order -> fully
// contiguous conflict-free ds_read_b128) + sX (20KB, XOR-swizzled granules ->
// <=2-way banks) via global_load_lds with pre-permuted per-lane global source
// (LDS dest stays lane-linear). One barrier, then 7 taps x 32 MFMAs per wave
// (4x8 register tile, 12 fragment reads per tap = 384 B LDS/MFMA vs 512
// before), barrier. NW_=256 halves block count -> weight L2 restage traffic
// 235MB -> 117MB and halves vmcnt(0) drain events. 76KB LDS -> 2 blocks/CU.
__global__ __launch_bounds__(256, 2) void tropconv_kernel(
        const __hip_bfloat16* __restrict__ exT,
        const __hip_bfloat16* __restrict__ ewb,
        const float* __restrict__ bias,
        float* __restrict__ out) {
    __shared__ __align__(16) __hip_bfloat16 smem[SW_ELEMS + SX_ELEMS]; // 77824 B
    __hip_bfloat16* sW = smem;             // fragment blocks: [t][og][lane*8]
    __hip_bfloat16* sX = smem + SX_ELEMS == nullptr ? nullptr : smem + SW_ELEMS; // [p][32ch] swizzled

    const int tid  = threadIdx.x;
    const int lane = tid & 63;
    const int wave = tid >> 6;
    const int wm   = wave >> 1;            // o half (64 each)
    const int wn   = wave & 1;             // w half (128 each)
    const int l15  = lane & 15;
    const int q    = lane >> 4;

    const int b  = blockIdx.y;
    const int w0 = blockIdx.x * NW_;
    const __hip_bfloat16* exb = exT + ((size_t)b * RPB + w0) * CIN_;

    f32x4 acc[4][8];
    #pragma unroll
    for (int i = 0; i < 4; ++i)
        #pragma unroll
        for (int j = 0; j < 8; ++j)
            acc[i][j] = (f32x4){0.f, 0.f, 0.f, 0.f};

    for (int c = 0; c < 4; ++c) {
        const int c0 = c * BC_;

        // ---- stage sW in fragment order: granule g -> frag block (t,og),
        // lane li holds W[og*16 + (li&15)][c0 + (li>>4)*8 .. +8].
        #pragma unroll
        for (int s = 0; s < 14; ++s) {
            int g  = tid + 256 * s;        // 0..3583, wave-aligned blocks of 64
            int li = g & 63;
            int blk = g >> 6;              // 0..55
            int t  = blk >> 3;
            int og = blk & 7;
            gl2lds16(ewb + ((((t << 7) + (og << 4) + (li & 15)) << 7) + c0 + ((li >> 4) << 3)),
                     &sW[g * 8]);
        }
        // ---- stage sX rows with granule-slot swizzle: slot j of row p holds
        // channel granule j ^ ((p>>1)&3). Rows >=262 stage garbage (in-ws,
        // never read by MFMAs); keeps rounds uniform (no divergent exec on
        // global_load_lds).
        #pragma unroll
        for (int s = 0; s < 5; ++s) {
            int gx = tid + 256 * s;        // 0..1279
            int p  = gx >> 2, j = gx & 3;
            int cj = j ^ ((p >> 1) & 3);
            gl2lds16(exb + ((size_t)p << 7) + c0 + (cj << 3), &sX[gx * 8]);
        }
        __syncthreads();   // drain global_load_lds; chunk resident

        #pragma unroll
        for (int t = 0; t < KW_; ++t) {
            bf16x8 af[4], bx[8];
            #pragma unroll
            for (int mi = 0; mi < 4; ++mi)   // contiguous 1024B per wave: conflict-free
                af[mi] = *(const bf16x8*)&sW[((t * 8 + wm * 4 + mi) << 9) + lane * 8];
            #pragma unroll
            for (int ni = 0; ni < 8; ++ni) {
                int p = wn * 128 + ni * 16 + l15 + t;   // input pos = out w + tap
                bx[ni] = *(const bf16x8*)&sX[(p << 5) + ((q ^ ((p >> 1) & 3)) << 3)];
            }
            #pragma unroll
            for (int mi = 0; mi < 4; ++mi)
                #pragma unroll
                for (int ni = 0; ni < 8; ++ni)
                    acc[mi][ni] = __builtin_amdgcn_mfma_f32_16x16x32_bf16(
                        af[mi], bx[ni], acc[mi][ni], 0, 0, 0);
        }
        __syncthreads();   // all readers done before restage
    }

    // epilogue: y = log(s) + bias[o]; C/D: col=lane&15 (w), row=q*4+reg (cout)
    float* outb = out + (size_t)b * COUT_ * L_;
    #pragma unroll
    for (int mi = 0; mi < 4; ++mi) {
        #pragma unroll
        for (int r = 0; r < 4; ++r) {
            int o = wm * 64 + mi * 16 + q * 4 + r;
            float bv = bias[o];
            #pragma unroll
            for (int ni = 0; ni < 8; ++ni) {
                int w = w0 + wn * 128 + ni * 16 + l15;
                outb[(size_t)o * L_ + w] = __logf(acc[mi][ni][r]) + bv;
            }
        }
    }
}

extern "C" void kernel_launch(void* const* d_in, const int* in_sizes, int n_in,
                              void* d_out, int out_size, void* d_ws, size_t ws_size,
                              hipStream_t stream) {
    const float* x    = (const float*)d_in[0];   // (32,128,4096) f32
    const float* wgt  = (const float*)d_in[1];   // (128,128,7)   f32
    const float* bias = (const float*)d_in[2];   // (128,)        f32
    float* out = (float*)d_out;                  // (32,128,4096) f32

    // workspace: exT (32 x 4104 x 128 bf16 = 33,619,968 B), then ewb (229 KB)
    __hip_bfloat16* exT = (__hip_bfloat16*)d_ws;
    __hip_bfloat16* ewb = (__hip_bfloat16*)((char*)d_ws + (size_t)B_N * RPB * CIN_ * 2);

    exp_x_kernel<<<dim3(64 + 18, B_N), 256, 0, stream>>>(x, exT, wgt, ewb);
    tropconv_kernel<<<dim3(L_ / NW_, B_N), 256, 0, stream>>>(exT, ewb, bias, out);
}